// Round 4
// baseline (15.007 us; speedup 1.0000x reference)
//
#include <hip/hip_runtime.h>

#define N_PTS  2048
#define T_FR   2
#define IMG    128
#define HW     (IMG * IMG)
#define BLOCK  512
#define WAVES  8
#define SEG    (N_PTS / WAVES)   // 256 gaussians per wave
// exp2 cutoff at 2^-26: q > QCUT -> weight < 2^-26 (x2048 gaussians -> <3e-5 err)
#define QCUT   36.043653f

#if defined(__has_builtin)
#if __has_builtin(__builtin_amdgcn_exp2f)
#define FAST_EXP2(x) __builtin_amdgcn_exp2f(x)
#endif
#endif
#ifndef FAST_EXP2
#define FAST_EXP2(x) exp2f(x)
#endif

__device__ __forceinline__ float sigmoid_fast(float x) {
    return 1.0f / (1.0f + FAST_EXP2(-1.44269504089f * x));
}
__device__ __forceinline__ float tanh_fast(float x) {
    return 1.0f - 2.0f / (FAST_EXP2(2.88539008178f * x) + 1.0f);
}
__device__ __forceinline__ float rdlane(float v, int l) {
    return __int_as_float(__builtin_amdgcn_readlane(__float_as_int(v), l));
}

__launch_bounds__(BLOCK, 4)
__global__ void gi_fused(const float* __restrict__ xyz,
                         const float* __restrict__ chol,
                         const float* __restrict__ opa,
                         const float* __restrict__ feat,
                         const float* __restrict__ tv,
                         float* __restrict__ out) {
    __shared__ float red[BLOCK * 3];   // only LDS left: cross-wave reduce

    const int bid  = blockIdx.x;
    const int t    = bid >> 8;          // 256 tiles per frame
    const int tile = bid & 255;
    const int h0   = (tile >> 4) << 3;
    const int w0   = (tile & 15) << 3;
    const int tid  = threadIdx.x;
    const int lane = tid & 63;
    const int wv   = tid >> 6;

    const float tt = tv[t];
    const float t2 = tt * tt;
    const float K  = -0.72134752044f;   // -0.5 * log2(e)
    const float cx = (float)w0 + 4.0f;  // tile center; pixel centers span +-3.5
    const float cy = (float)h0 + 4.0f;
    const float px = (float)(w0 + (lane & 7)) + 0.5f;
    const float py = (float)(h0 + (lane >> 3)) + 0.5f;

    float accr = 0.0f, accg = 0.0f, accb = 0.0f;

    // ---- per-wave sweep: compute 64 gaussians' params, then readlane-broadcast hits ----
#pragma unroll
    for (int j = 0; j < SEG / 64; ++j) {
        const int g = wv * SEG + j * 64 + lane;

        const float2 x0 = *(const float2*)&xyz[g * 2];
        const float2 x1 = *(const float2*)&xyz[N_PTS * 2 + g * 2];
        const float2 x2 = *(const float2*)&xyz[2 * N_PTS * 2 + g * 2];
        float mx = 64.0f * (tanh_fast(fmaf(t2, x2.x, fmaf(tt, x1.x, x0.x))) + 1.0f);
        float my = 64.0f * (tanh_fast(fmaf(t2, x2.y, fmaf(tt, x1.y, x0.y))) + 1.0f);

        float l0 = fmaf(t2, chol[2 * N_PTS * 3 + g * 3 + 0],
                   fmaf(tt, chol[N_PTS * 3 + g * 3 + 0], chol[g * 3 + 0])) + 0.5f;
        float l1 = fmaf(t2, chol[2 * N_PTS * 3 + g * 3 + 1],
                   fmaf(tt, chol[N_PTS * 3 + g * 3 + 1], chol[g * 3 + 1]));
        float l2 = fmaf(t2, chol[2 * N_PTS * 3 + g * 3 + 2],
                   fmaf(tt, chol[N_PTS * 3 + g * 3 + 2], chol[g * 3 + 2])) + 0.5f;

        float s11 = l0 * l0;
        float s12 = l0 * l1;
        float s22 = fmaf(l1, l1, l2 * l2);

        bool hit = (fabsf(mx - cx) <= sqrtf(QCUT * s11) + 3.5f) &&
                   (fabsf(my - cy) <= sqrtf(QCUT * s22) + 3.5f);

        float pa = 0.0f, pb2 = 0.0f, pc = 0.0f, pr = 0.0f, pg = 0.0f, pb = 0.0f;
        if (hit) {   // hit-only params, exec-masked
            float det  = fmaf(s11, s22, -s12 * s12);
            float Kinv = K / det;
            pa  = s22 * Kinv;
            pb2 = -2.0f * s12 * Kinv;
            pc  = s11 * Kinv;
            float po = fmaf(t2, opa[2 * N_PTS + g], fmaf(tt, opa[N_PTS + g], opa[g]));
            float op = sigmoid_fast(po);
            pr = op * sigmoid_fast(feat[g * 3 + 0]);
            pg = op * sigmoid_fast(feat[g * 3 + 1]);
            pb = op * sigmoid_fast(feat[g * 3 + 2]);
        }

        // wave-uniform scalar loop over hit lanes, ascending index -> deterministic
        unsigned long long m = __ballot(hit);
        while (m) {
            int l = __builtin_ctzll(m);
            m &= m - 1ull;
            float bmx = rdlane(mx, l),  bmy = rdlane(my, l);
            float ba  = rdlane(pa, l),  bb2 = rdlane(pb2, l), bc = rdlane(pc, l);
            float br  = rdlane(pr, l),  bg  = rdlane(pg, l),  bb = rdlane(pb, l);
            float dx = bmx - px;
            float dy = bmy - py;
            float t1 = fmaf(ba, dx, bb2 * dy);       // a'*dx + b2'*dy
            float q  = fmaf(bc * dy, dy, t1 * dx);   // + c'*dy^2
            float wgt = FAST_EXP2(q);
            accr = fmaf(wgt, br, accr);
            accg = fmaf(wgt, bg, accg);
            accb = fmaf(wgt, bb, accb);
        }
    }

    red[tid * 3 + 0] = accr;
    red[tid * 3 + 1] = accg;
    red[tid * 3 + 2] = accb;
    __syncthreads();

    // ---- deterministic fixed-order reduce over the 8 waves ----
    if (tid < 64) {
        float rr = 0.0f, gg = 0.0f, bb = 0.0f;
#pragma unroll
        for (int w8 = 0; w8 < WAVES; ++w8) {
            rr += red[(w8 * 64 + tid) * 3 + 0];
            gg += red[(w8 * 64 + tid) * 3 + 1];
            bb += red[(w8 * 64 + tid) * 3 + 2];
        }
        const int h   = h0 + (tid >> 3);
        const int w   = w0 + (tid & 7);
        const int pix = h * IMG + w;
        out[(t * 3 + 0) * HW + pix] = fminf(fmaxf(rr, 0.0f), 1.0f);
        out[(t * 3 + 1) * HW + pix] = fminf(fmaxf(gg, 0.0f), 1.0f);
        out[(t * 3 + 2) * HW + pix] = fminf(fmaxf(bb, 0.0f), 1.0f);
    }
}

extern "C" void kernel_launch(void* const* d_in, const int* in_sizes, int n_in,
                              void* d_out, int out_size, void* d_ws, size_t ws_size,
                              hipStream_t stream) {
    const float* xyz  = (const float*)d_in[0];  // [3, N, 2]
    const float* chol = (const float*)d_in[1];  // [3, N, 3]
    const float* opa  = (const float*)d_in[2];  // [3, N, 1]
    const float* feat = (const float*)d_in[3];  // [N, 3]
    const float* tv   = (const float*)d_in[4];  // [T]

    gi_fused<<<T_FR * 256, BLOCK, 0, stream>>>(
        xyz, chol, opa, feat, tv, (float*)d_out);
}

// Round 5
// 13.360 us; speedup vs baseline: 1.1233x; 1.1233x over previous
//
#include <hip/hip_runtime.h>

#define N_PTS  2048
#define T_FR   2
#define IMG    128
#define HW     (IMG * IMG)
#define BLOCK  512
#define WAVES  8
#define SEG    256              // gaussians per wave-chunk
// exp2 cutoff at 2^-26: q > QCUT -> weight < 2^-26 (x2048 gaussians -> <3e-5 err)
#define QCUT   36.043653f

#if defined(__has_builtin)
#if __has_builtin(__builtin_amdgcn_exp2f)
#define FAST_EXP2(x) __builtin_amdgcn_exp2f(x)
#endif
#endif
#ifndef FAST_EXP2
#define FAST_EXP2(x) exp2f(x)
#endif

__device__ __forceinline__ float sigmoid_fast(float x) {
    return 1.0f / (1.0f + FAST_EXP2(-1.44269504089f * x));
}
__device__ __forceinline__ float tanh_fast(float x) {
    return 1.0f - 2.0f / (FAST_EXP2(2.88539008178f * x) + 1.0f);
}

__launch_bounds__(BLOCK, 4)
__global__ void gi_fused(const float* __restrict__ xyz,
                         const float* __restrict__ chol,
                         const float* __restrict__ opa,
                         const float* __restrict__ feat,
                         const float* __restrict__ tv,
                         float* __restrict__ out) {
    __shared__ float4 sA[WAVES][SEG];   // {mx, my, a', b2'}
    __shared__ float4 sB[WAVES][SEG];   // {c', op*r, op*g, op*b}
    __shared__ int    sCnt[WAVES];
    __shared__ float  red[BLOCK * 3];

    const int bid  = blockIdx.x;
    const int t    = bid >> 8;          // 256 tiles per frame
    const int tile = bid & 255;
    const int h0   = (tile >> 4) << 3;
    const int w0   = (tile & 15) << 3;
    const int tid  = threadIdx.x;
    const int lane = tid & 63;
    const int wv   = tid >> 6;

    const float tt = tv[t];
    const float t2 = tt * tt;
    const float K  = -0.72134752044f;   // -0.5 * log2(e)
    const float cx = (float)w0 + 4.0f;  // tile center; pixel centers span +-3.5
    const float cy = (float)h0 + 4.0f;

    // ---- Phase 1: per-wave param compute + sqrt-free cull + ballot compaction ----
    int cnt = 0;
#pragma unroll 4
    for (int j = 0; j < SEG / 64; ++j) {
        const int g = wv * SEG + j * 64 + lane;

        const float2 x0 = *(const float2*)&xyz[g * 2];
        const float2 x1 = *(const float2*)&xyz[N_PTS * 2 + g * 2];
        const float2 x2 = *(const float2*)&xyz[2 * N_PTS * 2 + g * 2];
        float mx = 64.0f * (tanh_fast(fmaf(t2, x2.x, fmaf(tt, x1.x, x0.x))) + 1.0f);
        float my = 64.0f * (tanh_fast(fmaf(t2, x2.y, fmaf(tt, x1.y, x0.y))) + 1.0f);

        float l0 = fmaf(t2, chol[2 * N_PTS * 3 + g * 3 + 0],
                   fmaf(tt, chol[N_PTS * 3 + g * 3 + 0], chol[g * 3 + 0])) + 0.5f;
        float l1 = fmaf(t2, chol[2 * N_PTS * 3 + g * 3 + 1],
                   fmaf(tt, chol[N_PTS * 3 + g * 3 + 1], chol[g * 3 + 1]));
        float l2 = fmaf(t2, chol[2 * N_PTS * 3 + g * 3 + 2],
                   fmaf(tt, chol[N_PTS * 3 + g * 3 + 2], chol[g * 3 + 2])) + 0.5f;

        float s11 = l0 * l0;
        float s12 = l0 * l1;
        float s22 = fmaf(l1, l1, l2 * l2);

        // sqrt-free conservative bbox: max(|d|-3.5,0)^2 <= QCUT*s
        float ex = fmaxf(fabsf(mx - cx) - 3.5f, 0.0f);
        float ey = fmaxf(fabsf(my - cy) - 3.5f, 0.0f);
        bool hit = (ex * ex <= QCUT * s11) && (ey * ey <= QCUT * s22);

        unsigned long long m = __ballot(hit);
        if (hit) {
            float det  = fmaf(s11, s22, -s12 * s12);
            float Kinv = K / det;
            float po = fmaf(t2, opa[2 * N_PTS + g], fmaf(tt, opa[N_PTS + g], opa[g]));
            float op = sigmoid_fast(po);
            int pos = cnt + (int)__popcll(m & ((1ull << lane) - 1ull));
            sA[wv][pos] = make_float4(mx, my, s22 * Kinv, -2.0f * s12 * Kinv);
            sB[wv][pos] = make_float4(s11 * Kinv,
                                      op * sigmoid_fast(feat[g * 3 + 0]),
                                      op * sigmoid_fast(feat[g * 3 + 1]),
                                      op * sigmoid_fast(feat[g * 3 + 2]));
        }
        cnt += (int)__popcll(m);
    }
    if (lane == 0) sCnt[wv] = cnt;
    __syncthreads();

    // ---- Phase 2: each wave sweeps its own compacted segment, lane = pixel ----
    const float px = (float)(w0 + (lane & 7)) + 0.5f;
    const float py = (float)(h0 + (lane >> 3)) + 0.5f;
    const int   L  = __builtin_amdgcn_readfirstlane(sCnt[wv]);

    float ar0 = 0.0f, ag0 = 0.0f, ab0 = 0.0f;
    float ar1 = 0.0f, ag1 = 0.0f, ab1 = 0.0f;
    int i = 0;
    for (; i + 1 < L; i += 2) {          // 2x unroll, dual accumulators (fixed order)
        float4 A0 = sA[wv][i],     B0 = sB[wv][i];
        float4 A1 = sA[wv][i + 1], B1 = sB[wv][i + 1];
        float dx0 = A0.x - px, dy0 = A0.y - py;
        float dx1 = A1.x - px, dy1 = A1.y - py;
        float q0 = fmaf(B0.x * dy0, dy0, fmaf(A0.w, dy0, A0.z * dx0) * dx0);
        float q1 = fmaf(B1.x * dy1, dy1, fmaf(A1.w, dy1, A1.z * dx1) * dx1);
        float w0g = FAST_EXP2(q0);
        float w1g = FAST_EXP2(q1);
        ar0 = fmaf(w0g, B0.y, ar0); ag0 = fmaf(w0g, B0.z, ag0); ab0 = fmaf(w0g, B0.w, ab0);
        ar1 = fmaf(w1g, B1.y, ar1); ag1 = fmaf(w1g, B1.z, ag1); ab1 = fmaf(w1g, B1.w, ab1);
    }
    if (i < L) {
        float4 A0 = sA[wv][i], B0 = sB[wv][i];
        float dx0 = A0.x - px, dy0 = A0.y - py;
        float q0 = fmaf(B0.x * dy0, dy0, fmaf(A0.w, dy0, A0.z * dx0) * dx0);
        float w0g = FAST_EXP2(q0);
        ar0 = fmaf(w0g, B0.y, ar0); ag0 = fmaf(w0g, B0.z, ag0); ab0 = fmaf(w0g, B0.w, ab0);
    }

    red[tid * 3 + 0] = ar0 + ar1;
    red[tid * 3 + 1] = ag0 + ag1;
    red[tid * 3 + 2] = ab0 + ab1;
    __syncthreads();

    // ---- Phase 3: 3 waves reduce r/g/b channels in parallel (fixed order) ----
    if (tid < 192) {
        const int ch = tid >> 6;         // 0,1,2
        const int p  = tid & 63;
        float acc = 0.0f;
#pragma unroll
        for (int w8 = 0; w8 < WAVES; ++w8)
            acc += red[(w8 * 64 + p) * 3 + ch];
        const int h   = h0 + (p >> 3);
        const int w   = w0 + (p & 7);
        out[(t * 3 + ch) * HW + h * IMG + w] = fminf(fmaxf(acc, 0.0f), 1.0f);
    }
}

extern "C" void kernel_launch(void* const* d_in, const int* in_sizes, int n_in,
                              void* d_out, int out_size, void* d_ws, size_t ws_size,
                              hipStream_t stream) {
    const float* xyz  = (const float*)d_in[0];  // [3, N, 2]
    const float* chol = (const float*)d_in[1];  // [3, N, 3]
    const float* opa  = (const float*)d_in[2];  // [3, N, 1]
    const float* feat = (const float*)d_in[3];  // [N, 3]
    const float* tv   = (const float*)d_in[4];  // [T]

    gi_fused<<<T_FR * 256, BLOCK, 0, stream>>>(
        xyz, chol, opa, feat, tv, (float*)d_out);
}

// Round 6
// 11.787 us; speedup vs baseline: 1.2732x; 1.1335x over previous
//
#include <hip/hip_runtime.h>

#define N_PTS  2048
#define T_FR   2
#define IMG    128
#define HW     (IMG * IMG)
#define BLOCK  512
#define WAVES  8
#define SEG    256              // gaussians per wave-chunk (worst-case capacity)
// exp2 cutoff at 2^-26: q > QCUT -> weight < 2^-26 (x2048 gaussians -> <3e-5 err)
#define QCUT   36.043653f

#if defined(__has_builtin)
#if __has_builtin(__builtin_amdgcn_exp2f)
#define FAST_EXP2(x) __builtin_amdgcn_exp2f(x)
#endif
#endif
#ifndef FAST_EXP2
#define FAST_EXP2(x) exp2f(x)
#endif

__device__ __forceinline__ float sigmoid_fast(float x) {
    return 1.0f / (1.0f + FAST_EXP2(-1.44269504089f * x));
}
__device__ __forceinline__ float tanh_fast(float x) {
    return 1.0f - 2.0f / (FAST_EXP2(2.88539008178f * x) + 1.0f);
}

__launch_bounds__(BLOCK, 2)
__global__ void gi_fused(const float* __restrict__ xyz,
                         const float* __restrict__ chol,
                         const float* __restrict__ opa,
                         const float* __restrict__ feat,
                         const float* __restrict__ tv,
                         float* __restrict__ out) {
    __shared__ float4 sA[WAVES][SEG];    // {mx, my, a', b2'}
    __shared__ float4 sB[WAVES][SEG];    // {c', op*r, op*g, op*b}
    __shared__ int    sCnt[WAVES];
    __shared__ float  red[WAVES][128][3];  // 8 waves x 128 pixels x rgb

    const int bid  = blockIdx.x;
    const int t    = bid >> 7;           // 128 tiles (16x8) per frame
    const int tile = bid & 127;
    const int w0   = (tile & 7) << 4;    // 8 tiles across, 16 wide
    const int h0   = (tile >> 3) << 3;   // 16 tiles down, 8 tall
    const int tid  = threadIdx.x;
    const int lane = tid & 63;
    const int wv   = tid >> 6;

    const float tt = tv[t];
    const float t2 = tt * tt;
    const float K  = -0.72134752044f;    // -0.5 * log2(e)
    const float cx = (float)w0 + 8.0f;   // tile center; pixel centers span +-7.5 x, +-3.5 y
    const float cy = (float)h0 + 4.0f;

    // ---- Phase 1: per-wave param compute + sqrt-free cull + ballot compaction ----
    int cnt = 0;
#pragma unroll 4
    for (int j = 0; j < SEG / 64; ++j) {
        const int g = wv * SEG + j * 64 + lane;

        const float2 x0 = *(const float2*)&xyz[g * 2];
        const float2 x1 = *(const float2*)&xyz[N_PTS * 2 + g * 2];
        const float2 x2 = *(const float2*)&xyz[2 * N_PTS * 2 + g * 2];
        float mx = 64.0f * (tanh_fast(fmaf(t2, x2.x, fmaf(tt, x1.x, x0.x))) + 1.0f);
        float my = 64.0f * (tanh_fast(fmaf(t2, x2.y, fmaf(tt, x1.y, x0.y))) + 1.0f);

        float l0 = fmaf(t2, chol[2 * N_PTS * 3 + g * 3 + 0],
                   fmaf(tt, chol[N_PTS * 3 + g * 3 + 0], chol[g * 3 + 0])) + 0.5f;
        float l1 = fmaf(t2, chol[2 * N_PTS * 3 + g * 3 + 1],
                   fmaf(tt, chol[N_PTS * 3 + g * 3 + 1], chol[g * 3 + 1]));
        float l2 = fmaf(t2, chol[2 * N_PTS * 3 + g * 3 + 2],
                   fmaf(tt, chol[N_PTS * 3 + g * 3 + 2], chol[g * 3 + 2])) + 0.5f;

        float s11 = l0 * l0;
        float s12 = l0 * l1;
        float s22 = fmaf(l1, l1, l2 * l2);

        // sqrt-free conservative bbox: max(|d|-half_extent,0)^2 <= QCUT*s
        float ex = fmaxf(fabsf(mx - cx) - 7.5f, 0.0f);
        float ey = fmaxf(fabsf(my - cy) - 3.5f, 0.0f);
        bool hit = (ex * ex <= QCUT * s11) && (ey * ey <= QCUT * s22);

        unsigned long long m = __ballot(hit);
        if (hit) {
            float det  = fmaf(s11, s22, -s12 * s12);
            float Kinv = K / det;
            float po = fmaf(t2, opa[2 * N_PTS + g], fmaf(tt, opa[N_PTS + g], opa[g]));
            float op = sigmoid_fast(po);
            int pos = cnt + (int)__popcll(m & ((1ull << lane) - 1ull));
            sA[wv][pos] = make_float4(mx, my, s22 * Kinv, -2.0f * s12 * Kinv);
            sB[wv][pos] = make_float4(s11 * Kinv,
                                      op * sigmoid_fast(feat[g * 3 + 0]),
                                      op * sigmoid_fast(feat[g * 3 + 1]),
                                      op * sigmoid_fast(feat[g * 3 + 2]));
        }
        cnt += (int)__popcll(m);
    }
    if (lane == 0) sCnt[wv] = cnt;
    __syncthreads();

    // ---- Phase 2: wave sweeps its compacted segment; lane = 2 pixels (same column) ----
    const float px  = (float)(w0 + (lane & 15)) + 0.5f;
    const float py0 = (float)(h0 + (lane >> 4)) + 0.5f;
    const float py1 = py0 + 4.0f;
    const int   L   = __builtin_amdgcn_readfirstlane(sCnt[wv]);

    // acc[parity][pixel][ch]
    float r00 = 0, g00 = 0, b00 = 0, r01 = 0, g01 = 0, b01 = 0;
    float r10 = 0, g10 = 0, b10 = 0, r11 = 0, g11 = 0, b11 = 0;
    int i = 0;
    for (; i + 1 < L; i += 2) {
        float4 A0 = sA[wv][i],     B0 = sB[wv][i];
        float4 A1 = sA[wv][i + 1], B1 = sB[wv][i + 1];

        float dx0 = A0.x - px, az0 = A0.z * dx0;
        float dA0 = A0.y - py0, dB0 = A0.y - py1;
        float qA0 = fmaf(B0.x * dA0, dA0, fmaf(A0.w, dA0, az0) * dx0);
        float qB0 = fmaf(B0.x * dB0, dB0, fmaf(A0.w, dB0, az0) * dx0);
        float wA0 = FAST_EXP2(qA0), wB0 = FAST_EXP2(qB0);
        r00 = fmaf(wA0, B0.y, r00); g00 = fmaf(wA0, B0.z, g00); b00 = fmaf(wA0, B0.w, b00);
        r01 = fmaf(wB0, B0.y, r01); g01 = fmaf(wB0, B0.z, g01); b01 = fmaf(wB0, B0.w, b01);

        float dx1 = A1.x - px, az1 = A1.z * dx1;
        float dA1 = A1.y - py0, dB1 = A1.y - py1;
        float qA1 = fmaf(B1.x * dA1, dA1, fmaf(A1.w, dA1, az1) * dx1);
        float qB1 = fmaf(B1.x * dB1, dB1, fmaf(A1.w, dB1, az1) * dx1);
        float wA1 = FAST_EXP2(qA1), wB1 = FAST_EXP2(qB1);
        r10 = fmaf(wA1, B1.y, r10); g10 = fmaf(wA1, B1.z, g10); b10 = fmaf(wA1, B1.w, b10);
        r11 = fmaf(wB1, B1.y, r11); g11 = fmaf(wB1, B1.z, g11); b11 = fmaf(wB1, B1.w, b11);
    }
    if (i < L) {
        float4 A0 = sA[wv][i], B0 = sB[wv][i];
        float dx0 = A0.x - px, az0 = A0.z * dx0;
        float dA0 = A0.y - py0, dB0 = A0.y - py1;
        float qA0 = fmaf(B0.x * dA0, dA0, fmaf(A0.w, dA0, az0) * dx0);
        float qB0 = fmaf(B0.x * dB0, dB0, fmaf(A0.w, dB0, az0) * dx0);
        float wA0 = FAST_EXP2(qA0), wB0 = FAST_EXP2(qB0);
        r00 = fmaf(wA0, B0.y, r00); g00 = fmaf(wA0, B0.z, g00); b00 = fmaf(wA0, B0.w, b00);
        r01 = fmaf(wB0, B0.y, r01); g01 = fmaf(wB0, B0.z, g01); b01 = fmaf(wB0, B0.w, b01);
    }

    // pixel0 = lane (y0*16+x == lane), pixel1 = lane+64
    red[wv][lane][0]      = r00 + r10;
    red[wv][lane][1]      = g00 + g10;
    red[wv][lane][2]      = b00 + b10;
    red[wv][lane + 64][0] = r01 + r11;
    red[wv][lane + 64][1] = g01 + g11;
    red[wv][lane + 64][2] = b01 + b11;
    __syncthreads();

    // ---- Phase 3: 384 threads reduce 128 px x 3 ch in parallel (fixed order) ----
    if (tid < 384) {
        const int ch = tid >> 7;         // 0..2
        const int p  = tid & 127;
        float acc = 0.0f;
#pragma unroll
        for (int w8 = 0; w8 < WAVES; ++w8)
            acc += red[w8][p][ch];
        const int h = h0 + (p >> 4);
        const int w = w0 + (p & 15);
        out[(t * 3 + ch) * HW + h * IMG + w] = fminf(fmaxf(acc, 0.0f), 1.0f);
    }
}

extern "C" void kernel_launch(void* const* d_in, const int* in_sizes, int n_in,
                              void* d_out, int out_size, void* d_ws, size_t ws_size,
                              hipStream_t stream) {
    const float* xyz  = (const float*)d_in[0];  // [3, N, 2]
    const float* chol = (const float*)d_in[1];  // [3, N, 3]
    const float* opa  = (const float*)d_in[2];  // [3, N, 1]
    const float* feat = (const float*)d_in[3];  // [N, 3]
    const float* tv   = (const float*)d_in[4];  // [T]

    gi_fused<<<T_FR * 128, BLOCK, 0, stream>>>(
        xyz, chol, opa, feat, tv, (float*)d_out);
}